// Round 9
// baseline (271.221 us; speedup 1.0000x reference)
//
#include <hip/hip_runtime.h>
#include <hip/hip_bf16.h>

#define N_NODES_C 100000
#define N_PAD_C   100096   // padded to multiple of 128 for k1 tiles
#define N_RELS_C  237
#define N_EDGES_C 500000
#define D 128

typedef __attribute__((ext_vector_type(8))) short short8;
typedef __attribute__((ext_vector_type(4))) float f32x4;

__device__ __forceinline__ ushort f2bf(float x) {
    union { float f; uint u; } v; v.f = x;
    uint r = v.u + 0x7FFFu + ((v.u >> 16) & 1u);   // RNE
    return (ushort)(r >> 16);
}
__device__ __forceinline__ float bf2f_hi(uint u) {  // bits already in high half
    union { uint u; float f; } v; v.u = u; return v.f;
}

// ============ K0: all weight-side prep in one kernel =============
// grid (128, 3), 128 threads. j = blockIdx.x = output column.
// y=0: WfTb[j][k]   = bf16( sum_i W_ent[k][i]*W_ent2[i][j] )       (A path)
// y=1: WfTb[128+j][k]= bf16( sum_i W_ent[k][i]*W_ent2[128+i][j] )  (B path)
// y=2: WR col j kept in LDS -> RmB[r][j], sR[r] (+atomic), biasC[j],
//      sConst (+atomic).  sR/sConst are zero-initialized by the host memset.
__global__ void k_fuse_all(const float* __restrict__ W_ent, const float* __restrict__ W_rel,
                           const float* __restrict__ W_ent2,
                           const float* __restrict__ b_ent, const float* __restrict__ b_rel,
                           const float* __restrict__ b_ent2,
                           const float* __restrict__ relE,
                           const float* __restrict__ a_w, const float* __restrict__ a_b,
                           ushort* __restrict__ WfTb, ushort* __restrict__ RmB,
                           float* __restrict__ biasC, float* __restrict__ sR,
                           float* __restrict__ sConst) {
    int j = blockIdx.x;      // output col 0..127
    int t = threadIdx.x;     // 0..127
    int y = blockIdx.y;
    if (y == 0) {
        float acc = 0.f;
        for (int i = 0; i < D; ++i) acc += W_ent[t*D+i] * W_ent2[i*D+j];
        WfTb[j*D + t] = f2bf(acc);
    } else if (y == 1) {
        float acc = 0.f;
        for (int i = 0; i < D; ++i) acc += W_ent[t*D+i] * W_ent2[(D+i)*D+j];
        WfTb[(D+j)*D + t] = f2bf(acc);
    } else {
        __shared__ float wcol[128];
        __shared__ float red[128];
        float acc = 0.f;
        for (int i = 0; i < D; ++i) acc += W_rel[t*D+i] * W_ent2[(2*D+i)*D+j];
        wcol[t] = acc;
        red[t] = b_ent[t]*(W_ent2[t*D+j] + W_ent2[(D+t)*D+j]) + b_rel[t]*W_ent2[(2*D+t)*D+j];
        __syncthreads();
        for (int s = 64; s > 0; s >>= 1) { if (t < s) red[t] += red[t+s]; __syncthreads(); }
        if (t == 0) {
            float bC = red[0] + b_ent2[j];
            biasC[j] = bC;
            float contrib = bC * a_w[j];
            if (j == 0) contrib += a_b[0];
            atomicAdd(sConst, contrib);
        }
        float awj = a_w[j];
        for (int r = t; r < N_RELS_C; r += 128) {
            float rv = 0.f;
            for (int k = 0; k < D; ++k) rv += relE[r*D+k] * wcol[k];
            RmB[r*D + j] = f2bf(rv);
            atomicAdd(&sR[r], rv * awj);
        }
    }
}

// ============ K1: MFMA node GEMM + fused prep =============
// [An|Bn] = ent(fp32 -> bf16 in-register) @ WfT(256x128 bf16), fp32 acc.
// 512-thread block = 8 waves: waves 0-3 -> A-half, waves 4-7 -> B-half, same
// 128 rows (paired waves load identical ent rows -> L1 dedupe). Per-wave
// acc[2][8] = 64 VGPRs; __launch_bounds__(512,4) caps VGPR at 128 -> 16 waves/CU
// with the 64 KB W LDS (2 blocks/CU). Single __syncthreads after staging.
// Outputs: AnB bf16, BnB bf16, and fused sA/sB = (A|B)@a_w.
__global__ __launch_bounds__(512, 4) void k1_mfma(const float* __restrict__ ent,
                                                  const ushort* __restrict__ WfTb,
                                                  const float* __restrict__ a_w,
                                                  ushort* __restrict__ AnB,
                                                  ushort* __restrict__ BnB,
                                                  float* __restrict__ sA,
                                                  float* __restrict__ sB,
                                                  int n_nodes) {
    __shared__ __align__(16) ushort wL[256*128];   // 64 KB, both halves
    int tid = threadIdx.x;
    int m0 = blockIdx.x * 128;

    // stage W: 256 rows x 16 (16B units), swizzled unit col = k16 ^ (r&15)
#pragma unroll
    for (int u = 0; u < 8; ++u) {
        int f = u*512 + tid;          // 0..4095
        int r = f >> 4, k16 = f & 15;
        *(uint4*)&wL[r*128 + ((k16 ^ (r & 15)) << 3)] =
            *(const uint4*)&WfTb[r*128 + (k16 << 3)];
    }
    __syncthreads();

    int wave = tid >> 6, lane = tid & 63;
    int ny = wave >> 2;                 // 0 = A-half, 1 = B-half
    int q = lane >> 4, c = lane & 15;
    int wm = (wave & 3) * 32;           // 4 row-tiles x 32 rows = 128 rows

    f32x4 acc[2][8];
#pragma unroll
    for (int mt = 0; mt < 2; ++mt)
#pragma unroll
        for (int nt = 0; nt < 8; ++nt) { f32x4 z = {0.f,0.f,0.f,0.f}; acc[mt][nt] = z; }

#pragma unroll
    for (int chunk = 0; chunk < 4; ++chunk) {
        int k16 = chunk*4 + q;
        short8 a[2];
#pragma unroll
        for (int mt = 0; mt < 2; ++mt) {
            int row = m0 + wm + mt*16 + c;
            float4 e0 = make_float4(0.f,0.f,0.f,0.f), e1 = e0;
            if (row < n_nodes) {
                const float* ep = &ent[(size_t)row*D + (k16 << 3)];
                e0 = *(const float4*)ep;
                e1 = *(const float4*)(ep + 4);
            }
            short8 pk;
            pk[0]=(short)f2bf(e0.x); pk[1]=(short)f2bf(e0.y); pk[2]=(short)f2bf(e0.z); pk[3]=(short)f2bf(e0.w);
            pk[4]=(short)f2bf(e1.x); pk[5]=(short)f2bf(e1.y); pk[6]=(short)f2bf(e1.z); pk[7]=(short)f2bf(e1.w);
            a[mt] = pk;
        }
#pragma unroll
        for (int nt = 0; nt < 8; ++nt) {
            int wrow = ny*128 + nt*16 + c;     // wrow&15 == c
            short8 b = *(const short8*)&wL[wrow*128 + ((k16 ^ c) << 3)];
            acc[0][nt] = __builtin_amdgcn_mfma_f32_16x16x32_bf16(a[0], b, acc[0][nt], 0, 0, 0);
            acc[1][nt] = __builtin_amdgcn_mfma_f32_16x16x32_bf16(a[1], b, acc[1][nt], 0, 0, 0);
        }
    }

    // a_w values this lane needs for the sA/sB reduction: col = nt*16 + c
    float aw[8];
#pragma unroll
    for (int nt = 0; nt < 8; ++nt) aw[nt] = a_w[nt*16 + c];

    ushort* out  = ny ? BnB : AnB;
    float*  sOut = ny ? sB  : sA;

    // epilogue: C/D layout col=lane&15, row=q*4+reg
#pragma unroll
    for (int mt = 0; mt < 2; ++mt) {
#pragma unroll
        for (int reg = 0; reg < 4; ++reg) {
            int m = m0 + wm + mt*16 + q*4 + reg;
            float pa = 0.f;
#pragma unroll
            for (int nt = 0; nt < 8; ++nt) pa += acc[mt][nt][reg] * aw[nt];
#pragma unroll
            for (int msk = 1; msk < 16; msk <<= 1) pa += __shfl_xor(pa, msk);
            if (m < n_nodes) {
                if (c == 0) sOut[m] = pa;
#pragma unroll
                for (int nt = 0; nt < 8; ++nt)
                    out[(size_t)m*D + nt*16 + c] = f2bf(acc[mt][nt][reg]);
            }
        }
    }
}

// ============ K2: CSR build (4 edges/thread, int4 triplet decode) =============
__global__ void k_hist(const int* __restrict__ trip, int* __restrict__ deg, int n_edges) {
    int e0 = (blockIdx.x*256 + threadIdx.x) * 4;
    if (e0 >= n_edges) return;
    int4 w0 = *(const int4*)&trip[e0*3];
    int4 w1 = *(const int4*)&trip[e0*3 + 4];
    int4 w2 = *(const int4*)&trip[e0*3 + 8];
    int s[4] = {w0.x, w0.w, w1.z, w2.y};
#pragma unroll
    for (int u = 0; u < 4; ++u) {
        if (e0 + u >= n_edges) break;
        if ((unsigned)s[u] >= (unsigned)N_NODES_C) continue;   // guard
        atomicAdd(&deg[s[u]], 1);
    }
}

// hierarchical 3-kernel scan (round-4 proven: coalesced, ~5 us combined)
__global__ void k_scan1(const int* __restrict__ deg, int* __restrict__ off,
                        int* __restrict__ bsum, int n) {
    __shared__ int s[1024];
    int i = blockIdx.x*1024 + threadIdx.x;
    int v = (i < n) ? deg[i] : 0;
    s[threadIdx.x] = v; __syncthreads();
    for (int d = 1; d < 1024; d <<= 1) {
        int t = (threadIdx.x >= d) ? s[threadIdx.x - d] : 0;
        __syncthreads();
        s[threadIdx.x] += t;
        __syncthreads();
    }
    if (i < n) off[i] = s[threadIdx.x] - v;          // exclusive, pre-block-offset
    if (threadIdx.x == 1023) bsum[blockIdx.x] = s[1023];
}

__global__ void k_scan2(int* __restrict__ bsum, int nb) {
    __shared__ int s[128];
    int v = (threadIdx.x < nb) ? bsum[threadIdx.x] : 0;
    s[threadIdx.x] = v; __syncthreads();
    for (int d = 1; d < 128; d <<= 1) {
        int t = (threadIdx.x >= d) ? s[threadIdx.x - d] : 0;
        __syncthreads();
        s[threadIdx.x] += t;
        __syncthreads();
    }
    if (threadIdx.x < nb) bsum[threadIdx.x] = s[threadIdx.x] - v;  // exclusive, in-place
}

__global__ void k_scan3(int* __restrict__ off, int* __restrict__ cursor,
                        const int* __restrict__ bsum, int n, int total_edges) {
    int i = blockIdx.x*1024 + threadIdx.x;
    if (i < n) {
        int o = off[i] + bsum[blockIdx.x];
        off[i] = o;
        cursor[i] = o;
    }
    if (i == 0) off[n] = total_edges;
}

// ============ K2c: scatter (key, sB[dst]+sR[rel]) record into CSR slot ============
// 4 edges/thread, int4 triplet decode. exp lives in k_aggregate.
__global__ void k_edge_b(const int* __restrict__ trip, const float* __restrict__ sB,
                         const float* __restrict__ sR, int* __restrict__ cursor,
                         uint2* __restrict__ kb, int n_edges) {
    int e0 = (blockIdx.x*256 + threadIdx.x) * 4;
    if (e0 >= n_edges) return;
    int4 w0 = *(const int4*)&trip[e0*3];
    int4 w1 = *(const int4*)&trip[e0*3 + 4];
    int4 w2 = *(const int4*)&trip[e0*3 + 8];
    int s[4] = {w0.x, w0.w, w1.z, w2.y};
    int d[4] = {w0.y, w1.x, w1.w, w2.z};
    int r[4] = {w0.z, w1.y, w2.x, w2.w};
#pragma unroll
    for (int u = 0; u < 4; ++u) {
        if (e0 + u >= n_edges) break;
        if ((unsigned)s[u] >= (unsigned)N_NODES_C || (unsigned)d[u] >= (unsigned)N_NODES_C ||
            (unsigned)r[u] >= (unsigned)N_RELS_C) continue;   // guard (matches k_hist)
        float v = sB[d[u]] + sR[r[u]];
        int p = atomicAdd(&cursor[s[u]], 1);
        kb[p] = make_uint2((uint)(d[u] | (r[u] << 20)), __float_as_uint(v));
    }
}

// ============ K3: single-pass node-major aggregation, 8 lanes/node =============
// h[n] = An[n] + biasC + num/den, num = sum_e b_e*(B[dst]+R[rel]), den = sum_e b_e,
// b_e = exp(leaky(sA[n] + v_e + const)). 8 lanes per node (8 chains/wave),
// 2 x uint4 = 16 bf16 per lane per row; den is lane-redundant (no reduce).
__global__ void k_aggregate(const int* __restrict__ off, const uint2* __restrict__ kb,
                            const ushort* __restrict__ AnB, const ushort* __restrict__ BnB,
                            const ushort* __restrict__ RmB, const float* __restrict__ biasC,
                            const float* __restrict__ sA, const float* __restrict__ sConst,
                            float* __restrict__ h, int n_nodes) {
    int g = threadIdx.x >> 3, lane = threadIdx.x & 7;
    int n = blockIdx.x*32 + g;
    if (n >= n_nodes) return;
    int o0 = off[n], o1 = off[n+1];
    int c = lane*16;
    float* hp = &h[(size_t)n*D + c];
    if (o0 == o1) {
        float4 z = make_float4(0.f,0.f,0.f,0.f);
        *(float4*)hp = z; *(float4*)(hp+4) = z; *(float4*)(hp+8) = z; *(float4*)(hp+12) = z;
        return;
    }
    float t = sA[n] + sConst[0];
    float num[16];
#pragma unroll
    for (int i = 0; i < 16; ++i) num[i] = 0.f;
    float den = 0.f;

    int p = o0;
    for (; p + 4 <= o1; p += 4) {
        uint2 kv[4]; uint4 gB[4][2], gR[4][2];
#pragma unroll
        for (int u = 0; u < 4; ++u) kv[u] = kb[p+u];
#pragma unroll
        for (int u = 0; u < 4; ++u) {
            const ushort* bp = &BnB[(size_t)(kv[u].x & 0xFFFFF)*D + c];
            gB[u][0] = *(const uint4*)bp;
            gB[u][1] = *(const uint4*)(bp + 8);
            const ushort* rp = &RmB[(size_t)(kv[u].x >> 20)*D + c];
            gR[u][0] = *(const uint4*)rp;
            gR[u][1] = *(const uint4*)(rp + 8);
        }
#pragma unroll
        for (int u = 0; u < 4; ++u) {
            float logit = t + __uint_as_float(kv[u].y);
            float l = logit > 0.f ? logit : 0.01f*logit;
            float b = expf(l);
            den += b;
#pragma unroll
            for (int half = 0; half < 2; ++half) {
                const uint* bu = (const uint*)&gB[u][half];
                const uint* ru = (const uint*)&gR[u][half];
#pragma unroll
                for (int i = 0; i < 4; ++i) {
                    num[half*8 + 2*i]     += b * (bf2f_hi(bu[i] << 16)         + bf2f_hi(ru[i] << 16));
                    num[half*8 + 2*i + 1] += b * (bf2f_hi(bu[i] & 0xFFFF0000u) + bf2f_hi(ru[i] & 0xFFFF0000u));
                }
            }
        }
    }
    for (; p < o1; ++p) {
        uint2 kv = kb[p];
        float logit = t + __uint_as_float(kv.y);
        float l = logit > 0.f ? logit : 0.01f*logit;
        float b = expf(l);
        den += b;
        const ushort* bp = &BnB[(size_t)(kv.x & 0xFFFFF)*D + c];
        const ushort* rp = &RmB[(size_t)(kv.x >> 20)*D + c];
        uint4 gB0 = *(const uint4*)bp, gB1 = *(const uint4*)(bp + 8);
        uint4 gR0 = *(const uint4*)rp, gR1 = *(const uint4*)(rp + 8);
#pragma unroll
        for (int half = 0; half < 2; ++half) {
            const uint* bu = (const uint*)(half ? &gB1 : &gB0);
            const uint* ru = (const uint*)(half ? &gR1 : &gR0);
#pragma unroll
            for (int i = 0; i < 4; ++i) {
                num[half*8 + 2*i]     += b * (bf2f_hi(bu[i] << 16)         + bf2f_hi(ru[i] << 16));
                num[half*8 + 2*i + 1] += b * (bf2f_hi(bu[i] & 0xFFFF0000u) + bf2f_hi(ru[i] & 0xFFFF0000u));
            }
        }
    }

    float inv = 1.f / den;
    const ushort* ap = &AnB[(size_t)n*D + c];
    uint4 a0 = *(const uint4*)ap, a1 = *(const uint4*)(ap + 8);
#pragma unroll
    for (int half = 0; half < 2; ++half) {
        const uint* au = (const uint*)(half ? &a1 : &a0);
        float4 bcL = *(const float4*)&biasC[c + half*8];
        float4 bcH = *(const float4*)&biasC[c + half*8 + 4];
        float4 oL, oH;
        oL.x = bf2f_hi(au[0] << 16)         + bcL.x + num[half*8+0]*inv;
        oL.y = bf2f_hi(au[0] & 0xFFFF0000u) + bcL.y + num[half*8+1]*inv;
        oL.z = bf2f_hi(au[1] << 16)         + bcL.z + num[half*8+2]*inv;
        oL.w = bf2f_hi(au[1] & 0xFFFF0000u) + bcL.w + num[half*8+3]*inv;
        oH.x = bf2f_hi(au[2] << 16)         + bcH.x + num[half*8+4]*inv;
        oH.y = bf2f_hi(au[2] & 0xFFFF0000u) + bcH.y + num[half*8+5]*inv;
        oH.z = bf2f_hi(au[3] << 16)         + bcH.z + num[half*8+6]*inv;
        oH.w = bf2f_hi(au[3] & 0xFFFF0000u) + bcH.w + num[half*8+7]*inv;
        *(float4*)(hp + half*8)     = oL;
        *(float4*)(hp + half*8 + 4) = oH;
    }
}

extern "C" void kernel_launch(void* const* d_in, const int* in_sizes, int n_in,
                              void* d_out, int out_size, void* d_ws, size_t ws_size,
                              hipStream_t stream) {
    const int*   trip   = (const int*)  d_in[0];
    const float* ent    = (const float*)d_in[1];
    const float* relE   = (const float*)d_in[2];
    const float* W_ent  = (const float*)d_in[3];
    const float* b_ent  = (const float*)d_in[4];
    const float* W_rel  = (const float*)d_in[5];
    const float* b_rel  = (const float*)d_in[6];
    const float* W_ent2 = (const float*)d_in[7];
    const float* b_ent2 = (const float*)d_in[8];
    const float* a_w    = (const float*)d_in[9];
    const float* a_b    = (const float*)d_in[10];
    float* h = (float*)d_out;

    // Workspace: ~57 MB total — stays under round 4's proven-safe 57.6 MB.
    char* ws = (char*)d_ws;
    size_t o = 0;
    auto alloc = [&](size_t bytes) { size_t p = o; o += (bytes + 255) & ~(size_t)255; return p; };
    ushort* WfTb   = (ushort*)(ws + alloc(256*128*2));
    float*  biasC  = (float*) (ws + alloc(128*4));
    ushort* RmB    = (ushort*)(ws + alloc((size_t)N_RELS_C*128*2));
    float*  sA     = (float*) (ws + alloc((size_t)N_NODES_C*4));
    float*  sB     = (float*) (ws + alloc((size_t)N_NODES_C*4));
    // --- contiguous zero-init region: sR, sConst, deg (single memset) ---
    size_t z0 = o;
    float*  sR     = (float*) (ws + alloc(N_RELS_C*4));
    float*  sConst = (float*) (ws + alloc(4));
    int*    deg    = (int*)   (ws + alloc((size_t)N_NODES_C*4));
    size_t z1 = o;
    // -------------------------------------------------------------------
    int*    off    = (int*)   (ws + alloc(((size_t)N_NODES_C+1)*4));
    int*    cursor = (int*)   (ws + alloc((size_t)N_NODES_C*4));
    int*    bsum   = (int*)   (ws + alloc(128*4));
    uint2*  kb     = (uint2*) (ws + alloc((size_t)N_EDGES_C*8));
    ushort* BnB    = (ushort*)(ws + alloc((size_t)N_PAD_C*128*2));
    ushort* AnB    = (ushort*)(ws + alloc((size_t)N_PAD_C*128*2));

    hipMemsetAsync(ws + z0, 0, z1 - z0, stream);

    k_fuse_all<<<dim3(128,3), 128, 0, stream>>>(W_ent, W_rel, W_ent2, b_ent, b_rel, b_ent2,
                                                relE, a_w, a_b, WfTb, RmB, biasC, sR, sConst);
    k1_mfma<<<N_PAD_C/128, 512, 0, stream>>>(ent, WfTb, a_w, AnB, BnB, sA, sB, N_NODES_C);
    k_hist<<<(N_EDGES_C/4 + 255)/256, 256, 0, stream>>>(trip, deg, N_EDGES_C);
    int nb = (N_NODES_C + 1023)/1024;   // 98
    k_scan1<<<nb, 1024, 0, stream>>>(deg, off, bsum, N_NODES_C);
    k_scan2<<<1, 128, 0, stream>>>(bsum, nb);
    k_scan3<<<nb, 1024, 0, stream>>>(off, cursor, bsum, N_NODES_C, N_EDGES_C);
    k_edge_b<<<(N_EDGES_C/4 + 255)/256, 256, 0, stream>>>(trip, sB, sR, cursor, kb, N_EDGES_C);
    k_aggregate<<<(N_NODES_C+31)/32, 256, 0, stream>>>(off, kb, AnB, BnB, RmB, biasC,
                                                       sA, sConst, h, N_NODES_C);
}

// Round 10
// 238.146 us; speedup vs baseline: 1.1389x; 1.1389x over previous
//
#include <hip/hip_runtime.h>
#include <hip/hip_bf16.h>

#define N_NODES_C 100000
#define N_PAD_C   100096   // padded to multiple of 128 for k1 tiles
#define N_RELS_C  237
#define N_EDGES_C 500000
#define D 128

typedef __attribute__((ext_vector_type(8))) short short8;
typedef __attribute__((ext_vector_type(4))) float f32x4;

__device__ __forceinline__ ushort f2bf(float x) {
    union { float f; uint u; } v; v.f = x;
    uint r = v.u + 0x7FFFu + ((v.u >> 16) & 1u);   // RNE
    return (ushort)(r >> 16);
}
__device__ __forceinline__ float bf2f_hi(uint u) {  // bits already in high half
    union { uint u; float f; } v; v.u = u; return v.f;
}

// ============ K0: fuse weights =============
// WfTb[j][k]   (j<128)  = sum_i W_ent[k][i] * W_ent2[i][j]      (A path, bf16, transposed)
// WfTb[128+j][k]        = sum_i W_ent[k][i] * W_ent2[128+i][j]  (B path)
// WR[k][j]              = sum_i W_rel[k][i] * W_ent2[256+i][j]
// biasC[j] = b_ent@(W1+W2) + b_rel@W3 + b_ent2
__global__ void k_fuse_w(const float* __restrict__ W_ent, const float* __restrict__ W_rel,
                         const float* __restrict__ W_ent2,
                         const float* __restrict__ b_ent, const float* __restrict__ b_rel,
                         const float* __restrict__ b_ent2,
                         float* __restrict__ WR, ushort* __restrict__ WfTb,
                         float* __restrict__ biasC) {
    int j = threadIdx.x;       // 0..127 output col
    int k = blockIdx.x;        // 0..127 row
    int which = blockIdx.y;    // 0..3
    if (which == 0) {
        float acc = 0.f;
        for (int i = 0; i < D; ++i) acc += W_ent[k*D+i] * W_ent2[i*D+j];
        WfTb[j*D + k] = f2bf(acc);
    } else if (which == 1) {
        float acc = 0.f;
        for (int i = 0; i < D; ++i) acc += W_ent[k*D+i] * W_ent2[(D+i)*D+j];
        WfTb[(D+j)*D + k] = f2bf(acc);
    } else if (which == 2) {
        float acc = 0.f;
        for (int i = 0; i < D; ++i) acc += W_rel[k*D+i] * W_ent2[(2*D+i)*D+j];
        WR[k*D + j] = acc;
    } else if (k == 0) {
        float acc = b_ent2[j];
        for (int i = 0; i < D; ++i) {
            acc += b_ent[i] * (W_ent2[i*D+j] + W_ent2[(D+i)*D+j]);
            acc += b_rel[i] * W_ent2[(2*D+i)*D+j];
        }
        biasC[j] = acc;
    }
}

// ============ K0b: relation table (bf16) + rel/const attention scalars =============
__global__ void k_rel_scalars(const float* __restrict__ rel_embed,
                              const float* __restrict__ a_w, const float* __restrict__ a_b,
                              const float* __restrict__ WR, const float* __restrict__ biasC,
                              ushort* __restrict__ RmB, float* __restrict__ sR,
                              float* __restrict__ sConst) {
    int j = threadIdx.x;   // 128 threads
    int b = blockIdx.x;    // 0..237
    __shared__ float red[128];
    if (b < N_RELS_C) {
        float acc = 0.f;
        for (int k = 0; k < D; ++k) acc += rel_embed[b*D+k] * WR[k*D+j];
        RmB[b*D+j] = f2bf(acc);
        red[j] = acc * a_w[j];
        __syncthreads();
        for (int s = 64; s > 0; s >>= 1) { if (j < s) red[j] += red[j+s]; __syncthreads(); }
        if (j == 0) sR[b] = red[0];
    } else {
        red[j] = biasC[j] * a_w[j];
        __syncthreads();
        for (int s = 64; s > 0; s >>= 1) { if (j < s) red[j] += red[j+s]; __syncthreads(); }
        if (j == 0) sConst[0] = red[0] + a_b[0];
    }
}

// ============ K1: MFMA node GEMM + fused prep =============
// [An|Bn] = ent(fp32 -> bf16 in-register) @ WfT(256x128 bf16), fp32 acc.
// 512-thread block = 8 waves: waves 0-3 -> A-half, waves 4-7 -> B-half, same
// 128 rows (paired waves load identical ent rows -> L1 dedupe). Per-wave
// acc[2][8] = 64 VGPRs; __launch_bounds__(512,4) caps VGPR at 128 -> 16 waves/CU
// with the 64 KB W LDS (2 blocks/CU). Single __syncthreads after staging.
// Outputs: AnB bf16, BnB bf16, and fused sA/sB = (A|B)@a_w.
__global__ __launch_bounds__(512, 4) void k1_mfma(const float* __restrict__ ent,
                                                  const ushort* __restrict__ WfTb,
                                                  const float* __restrict__ a_w,
                                                  ushort* __restrict__ AnB,
                                                  ushort* __restrict__ BnB,
                                                  float* __restrict__ sA,
                                                  float* __restrict__ sB,
                                                  int n_nodes) {
    __shared__ __align__(16) ushort wL[256*128];   // 64 KB, both halves
    int tid = threadIdx.x;
    int m0 = blockIdx.x * 128;

    // stage W: 256 rows x 16 (16B units), swizzled unit col = k16 ^ (r&15)
#pragma unroll
    for (int u = 0; u < 8; ++u) {
        int f = u*512 + tid;          // 0..4095
        int r = f >> 4, k16 = f & 15;
        *(uint4*)&wL[r*128 + ((k16 ^ (r & 15)) << 3)] =
            *(const uint4*)&WfTb[r*128 + (k16 << 3)];
    }
    __syncthreads();

    int wave = tid >> 6, lane = tid & 63;
    int ny = wave >> 2;                 // 0 = A-half, 1 = B-half
    int q = lane >> 4, c = lane & 15;
    int wm = (wave & 3) * 32;           // 4 row-tiles x 32 rows = 128 rows

    f32x4 acc[2][8];
#pragma unroll
    for (int mt = 0; mt < 2; ++mt)
#pragma unroll
        for (int nt = 0; nt < 8; ++nt) { f32x4 z = {0.f,0.f,0.f,0.f}; acc[mt][nt] = z; }

#pragma unroll
    for (int chunk = 0; chunk < 4; ++chunk) {
        int k16 = chunk*4 + q;
        short8 a[2];
#pragma unroll
        for (int mt = 0; mt < 2; ++mt) {
            int row = m0 + wm + mt*16 + c;
            float4 e0 = make_float4(0.f,0.f,0.f,0.f), e1 = e0;
            if (row < n_nodes) {
                const float* ep = &ent[(size_t)row*D + (k16 << 3)];
                e0 = *(const float4*)ep;
                e1 = *(const float4*)(ep + 4);
            }
            short8 pk;
            pk[0]=(short)f2bf(e0.x); pk[1]=(short)f2bf(e0.y); pk[2]=(short)f2bf(e0.z); pk[3]=(short)f2bf(e0.w);
            pk[4]=(short)f2bf(e1.x); pk[5]=(short)f2bf(e1.y); pk[6]=(short)f2bf(e1.z); pk[7]=(short)f2bf(e1.w);
            a[mt] = pk;
        }
#pragma unroll
        for (int nt = 0; nt < 8; ++nt) {
            int wrow = ny*128 + nt*16 + c;     // wrow&15 == c
            short8 b = *(const short8*)&wL[wrow*128 + ((k16 ^ c) << 3)];
            acc[0][nt] = __builtin_amdgcn_mfma_f32_16x16x32_bf16(a[0], b, acc[0][nt], 0, 0, 0);
            acc[1][nt] = __builtin_amdgcn_mfma_f32_16x16x32_bf16(a[1], b, acc[1][nt], 0, 0, 0);
        }
    }

    // a_w values this lane needs for the sA/sB reduction: col = nt*16 + c
    float aw[8];
#pragma unroll
    for (int nt = 0; nt < 8; ++nt) aw[nt] = a_w[nt*16 + c];

    ushort* out  = ny ? BnB : AnB;
    float*  sOut = ny ? sB  : sA;

    // epilogue: C/D layout col=lane&15, row=q*4+reg
#pragma unroll
    for (int mt = 0; mt < 2; ++mt) {
#pragma unroll
        for (int reg = 0; reg < 4; ++reg) {
            int m = m0 + wm + mt*16 + q*4 + reg;
            float pa = 0.f;
#pragma unroll
            for (int nt = 0; nt < 8; ++nt) pa += acc[mt][nt][reg] * aw[nt];
#pragma unroll
            for (int msk = 1; msk < 16; msk <<= 1) pa += __shfl_xor(pa, msk);
            if (m < n_nodes) {
                if (c == 0) sOut[m] = pa;
#pragma unroll
                for (int nt = 0; nt < 8; ++nt)
                    out[(size_t)m*D + nt*16 + c] = f2bf(acc[mt][nt][reg]);
            }
        }
    }
}

// ============ K2: CSR build =============
__global__ void k_hist(const int* __restrict__ trip, int* __restrict__ deg, int n_edges) {
    int e = blockIdx.x*256 + threadIdx.x;
    if (e >= n_edges) return;
    int s = trip[3*e];
    if ((unsigned)s >= (unsigned)N_NODES_C) return;   // guard (no-op on valid input)
    atomicAdd(&deg[s], 1);
}

// hierarchical 3-kernel scan (round-4 proven: coalesced, ~5 us combined)
__global__ void k_scan1(const int* __restrict__ deg, int* __restrict__ off,
                        int* __restrict__ bsum, int n) {
    __shared__ int s[1024];
    int i = blockIdx.x*1024 + threadIdx.x;
    int v = (i < n) ? deg[i] : 0;
    s[threadIdx.x] = v; __syncthreads();
    for (int d = 1; d < 1024; d <<= 1) {
        int t = (threadIdx.x >= d) ? s[threadIdx.x - d] : 0;
        __syncthreads();
        s[threadIdx.x] += t;
        __syncthreads();
    }
    if (i < n) off[i] = s[threadIdx.x] - v;          // exclusive, pre-block-offset
    if (threadIdx.x == 1023) bsum[blockIdx.x] = s[1023];
}

__global__ void k_scan2(int* __restrict__ bsum, int nb) {
    __shared__ int s[128];
    int v = (threadIdx.x < nb) ? bsum[threadIdx.x] : 0;
    s[threadIdx.x] = v; __syncthreads();
    for (int d = 1; d < 128; d <<= 1) {
        int t = (threadIdx.x >= d) ? s[threadIdx.x - d] : 0;
        __syncthreads();
        s[threadIdx.x] += t;
        __syncthreads();
    }
    if (threadIdx.x < nb) bsum[threadIdx.x] = s[threadIdx.x] - v;  // exclusive, in-place
}

__global__ void k_scan3(int* __restrict__ off, int* __restrict__ cursor,
                        const int* __restrict__ bsum, int n, int total_edges) {
    int i = blockIdx.x*1024 + threadIdx.x;
    if (i < n) {
        int o = off[i] + bsum[blockIdx.x];
        off[i] = o;
        cursor[i] = o;
    }
    if (i == 0) off[n] = total_edges;
}

// ============ K2c: scatter (key, sB[dst]+sR[rel]) record into CSR slot ============
// The exp lives in k_aggregate (sA[src]+const is node-uniform there).
__global__ void k_edge_b(const int* __restrict__ trip, const float* __restrict__ sB,
                         const float* __restrict__ sR, int* __restrict__ cursor,
                         uint2* __restrict__ kb, int n_edges) {
    int e = blockIdx.x*256 + threadIdx.x;
    if (e >= n_edges) return;
    int s = trip[3*e], d = trip[3*e+1], r = trip[3*e+2];
    if ((unsigned)s >= (unsigned)N_NODES_C || (unsigned)d >= (unsigned)N_NODES_C ||
        (unsigned)r >= (unsigned)N_RELS_C) return;   // guard (matches k_hist)
    float v = sB[d] + sR[r];
    int p = atomicAdd(&cursor[s], 1);
    kb[p] = make_uint2((uint)(d | (r << 20)), __float_as_uint(v));
}

// ============ K3: single-pass node-major aggregation, masked unroll-4 =============
// h[n] = An[n] + biasC + num/den, num = sum_e b_e*(B[dst]+R[rel]), den = sum_e b_e,
// b_e = exp(leaky(sA[n] + v_e + const)). 16 lanes per node (4 chains/wave).
// The edge loop is ALWAYS a 4-wide batch: indices clamped to o1-1, coefficient
// zeroed for invalid slots — every node gets 4-deep memory-level parallelism
// (no serial remainder chain; dup loads on the last batch are L1 hits).
__global__ void k_aggregate(const int* __restrict__ off, const uint2* __restrict__ kb,
                            const ushort* __restrict__ AnB, const ushort* __restrict__ BnB,
                            const ushort* __restrict__ RmB, const float* __restrict__ biasC,
                            const float* __restrict__ sA, const float* __restrict__ sConst,
                            float* __restrict__ h, int n_nodes) {
    int g = threadIdx.x >> 4, lane = threadIdx.x & 15;
    int n = blockIdx.x*16 + g;
    if (n >= n_nodes) return;
    int o0 = off[n], o1 = off[n+1];
    int c = lane*8;
    float* hp = &h[(size_t)n*D + c];
    if (o0 == o1) {
        *(float4*)hp     = make_float4(0.f,0.f,0.f,0.f);
        *(float4*)(hp+4) = make_float4(0.f,0.f,0.f,0.f);
        return;
    }
    float t = sA[n] + sConst[0];
    float num[8];
#pragma unroll
    for (int i = 0; i < 8; ++i) num[i] = 0.f;
    float den = 0.f;

    for (int p = o0; p < o1; p += 4) {
        uint2 kv[4]; uint4 gB[4], gR[4]; float vmask[4];
#pragma unroll
        for (int u = 0; u < 4; ++u) {
            int q = p + u;
            vmask[u] = (q < o1) ? 1.f : 0.f;
            int pc = (q < o1) ? q : (o1 - 1);
            kv[u] = kb[pc];
        }
#pragma unroll
        for (int u = 0; u < 4; ++u) {
            gB[u] = *(const uint4*)&BnB[(size_t)(kv[u].x & 0xFFFFF)*D + c];
            gR[u] = *(const uint4*)&RmB[(size_t)(kv[u].x >> 20)*D + c];
        }
#pragma unroll
        for (int u = 0; u < 4; ++u) {
            float logit = t + __uint_as_float(kv[u].y);
            float l = logit > 0.f ? logit : 0.01f*logit;
            float b = vmask[u] * expf(l);
            den += b;
            const uint* bu = (const uint*)&gB[u];
            const uint* ru = (const uint*)&gR[u];
#pragma unroll
            for (int i = 0; i < 4; ++i) {
                num[2*i]   += b * (bf2f_hi(bu[i] << 16)         + bf2f_hi(ru[i] << 16));
                num[2*i+1] += b * (bf2f_hi(bu[i] & 0xFFFF0000u) + bf2f_hi(ru[i] & 0xFFFF0000u));
            }
        }
    }

    float inv = 1.f / den;
    uint4 araw = *(const uint4*)&AnB[(size_t)n*D + c];
    const uint* au = (const uint*)&araw;
    float4 bc0 = *(const float4*)&biasC[c];
    float4 bc1 = *(const float4*)&biasC[c+4];
    float4 o0v, o1v;
    o0v.x = bf2f_hi(au[0] << 16)         + bc0.x + num[0]*inv;
    o0v.y = bf2f_hi(au[0] & 0xFFFF0000u) + bc0.y + num[1]*inv;
    o0v.z = bf2f_hi(au[1] << 16)         + bc0.z + num[2]*inv;
    o0v.w = bf2f_hi(au[1] & 0xFFFF0000u) + bc0.w + num[3]*inv;
    o1v.x = bf2f_hi(au[2] << 16)         + bc1.x + num[4]*inv;
    o1v.y = bf2f_hi(au[2] & 0xFFFF0000u) + bc1.y + num[5]*inv;
    o1v.z = bf2f_hi(au[3] << 16)         + bc1.z + num[6]*inv;
    o1v.w = bf2f_hi(au[3] & 0xFFFF0000u) + bc1.w + num[7]*inv;
    *(float4*)hp     = o0v;
    *(float4*)(hp+4) = o1v;
}

extern "C" void kernel_launch(void* const* d_in, const int* in_sizes, int n_in,
                              void* d_out, int out_size, void* d_ws, size_t ws_size,
                              hipStream_t stream) {
    const int*   trip   = (const int*)  d_in[0];
    const float* ent    = (const float*)d_in[1];
    const float* relE   = (const float*)d_in[2];
    const float* W_ent  = (const float*)d_in[3];
    const float* b_ent  = (const float*)d_in[4];
    const float* W_rel  = (const float*)d_in[5];
    const float* b_rel  = (const float*)d_in[6];
    const float* W_ent2 = (const float*)d_in[7];
    const float* b_ent2 = (const float*)d_in[8];
    const float* a_w    = (const float*)d_in[9];
    const float* a_b    = (const float*)d_in[10];
    float* h = (float*)d_out;

    // Workspace: ~57 MB total — stays under round 4's proven-safe 57.6 MB.
    char* ws = (char*)d_ws;
    size_t o = 0;
    auto alloc = [&](size_t bytes) { size_t p = o; o += (bytes + 255) & ~(size_t)255; return p; };
    float*  WR     = (float*) (ws + alloc(128*128*4));
    ushort* WfTb   = (ushort*)(ws + alloc(256*128*2));
    float*  biasC  = (float*) (ws + alloc(128*4));
    ushort* RmB    = (ushort*)(ws + alloc((size_t)N_RELS_C*128*2));
    float*  sR     = (float*) (ws + alloc(N_RELS_C*4));
    float*  sConst = (float*) (ws + alloc(4));
    float*  sA     = (float*) (ws + alloc((size_t)N_NODES_C*4));
    float*  sB     = (float*) (ws + alloc((size_t)N_NODES_C*4));
    int*    deg    = (int*)   (ws + alloc((size_t)N_NODES_C*4));
    int*    off    = (int*)   (ws + alloc(((size_t)N_NODES_C+1)*4));
    int*    cursor = (int*)   (ws + alloc((size_t)N_NODES_C*4));
    int*    bsum   = (int*)   (ws + alloc(128*4));
    uint2*  kb     = (uint2*) (ws + alloc((size_t)N_EDGES_C*8));
    ushort* BnB    = (ushort*)(ws + alloc((size_t)N_PAD_C*128*2));
    ushort* AnB    = (ushort*)(ws + alloc((size_t)N_PAD_C*128*2));

    hipMemsetAsync(deg, 0, (size_t)N_NODES_C*4, stream);

    k_fuse_w<<<dim3(128,4), 128, 0, stream>>>(W_ent, W_rel, W_ent2, b_ent, b_rel, b_ent2,
                                              WR, WfTb, biasC);
    k_rel_scalars<<<N_RELS_C+1, 128, 0, stream>>>(relE, a_w, a_b, WR, biasC,
                                                  RmB, sR, sConst);
    k1_mfma<<<N_PAD_C/128, 512, 0, stream>>>(ent, WfTb, a_w, AnB, BnB, sA, sB, N_NODES_C);
    k_hist<<<(N_EDGES_C+255)/256, 256, 0, stream>>>(trip, deg, N_EDGES_C);
    int nb = (N_NODES_C + 1023)/1024;   // 98
    k_scan1<<<nb, 1024, 0, stream>>>(deg, off, bsum, N_NODES_C);
    k_scan2<<<1, 128, 0, stream>>>(bsum, nb);
    k_scan3<<<nb, 1024, 0, stream>>>(off, cursor, bsum, N_NODES_C, N_EDGES_C);
    k_edge_b<<<(N_EDGES_C+255)/256, 256, 0, stream>>>(trip, sB, sR, cursor, kb, N_EDGES_C);
    k_aggregate<<<(N_NODES_C+15)/16, 256, 0, stream>>>(off, kb, AnB, BnB, RmB, biasC,
                                                       sA, sConst, h, N_NODES_C);
}

// Round 11
// 225.467 us; speedup vs baseline: 1.2029x; 1.0562x over previous
//
#include <hip/hip_runtime.h>
#include <hip/hip_bf16.h>

#define N_NODES_C 100000
#define N_PAD_C   100096   // padded to multiple of 128 for k1 tiles
#define N_RELS_C  237
#define N_EDGES_C 500000
#define D 128

#define NBLK_GEMM 782          // N_PAD_C/128
#define NBLK_REL  60           // ceil(237/4), 4 rel rows per 512-thr block
#define NBLK_HIST 128          // grid-stride histogram blocks

typedef __attribute__((ext_vector_type(8))) short short8;
typedef __attribute__((ext_vector_type(4))) float f32x4;

__device__ __forceinline__ ushort f2bf(float x) {
    union { float f; uint u; } v; v.f = x;
    uint r = v.u + 0x7FFFu + ((v.u >> 16) & 1u);   // RNE
    return (ushort)(r >> 16);
}
__device__ __forceinline__ float bf2f_hi(uint u) {  // bits already in high half
    union { uint u; float f; } v; v.u = u; return v.f;
}

// ============ K0: fuse weights + biasC + sConst + deg zeroing =============
// grid (128,4) x 128 thr.
// y=0: WfTb[j][k]    = bf16(W_ent @ W_ent2[0:128])   (A path, transposed)
// y=1: WfTb[128+j][k]= bf16(W_ent @ W_ent2[128:256]) (B path)
// y=2: WR[k][j]      = W_rel @ W_ent2[256:384]
// y=3,k=0: biasC[j] + sConst reduction; y=3,k>0: zero deg[] (replaces memset)
__global__ void k_fuse_w(const float* __restrict__ W_ent, const float* __restrict__ W_rel,
                         const float* __restrict__ W_ent2,
                         const float* __restrict__ b_ent, const float* __restrict__ b_rel,
                         const float* __restrict__ b_ent2,
                         const float* __restrict__ a_w, const float* __restrict__ a_b,
                         float* __restrict__ WR, ushort* __restrict__ WfTb,
                         float* __restrict__ biasC, float* __restrict__ sConst,
                         int* __restrict__ deg) {
    int j = threadIdx.x;       // 0..127
    int k = blockIdx.x;        // 0..127
    int which = blockIdx.y;    // 0..3
    if (which == 0) {
        float acc = 0.f;
        for (int i = 0; i < D; ++i) acc += W_ent[k*D+i] * W_ent2[i*D+j];
        WfTb[j*D + k] = f2bf(acc);
    } else if (which == 1) {
        float acc = 0.f;
        for (int i = 0; i < D; ++i) acc += W_ent[k*D+i] * W_ent2[(D+i)*D+j];
        WfTb[(D+j)*D + k] = f2bf(acc);
    } else if (which == 2) {
        float acc = 0.f;
        for (int i = 0; i < D; ++i) acc += W_rel[k*D+i] * W_ent2[(2*D+i)*D+j];
        WR[k*D + j] = acc;
    } else if (k == 0) {
        __shared__ float red[128];
        float acc = b_ent2[j];
        for (int i = 0; i < D; ++i) {
            acc += b_ent[i] * (W_ent2[i*D+j] + W_ent2[(D+i)*D+j]);
            acc += b_rel[i] * W_ent2[(2*D+i)*D+j];
        }
        biasC[j] = acc;
        red[j] = acc * a_w[j];
        __syncthreads();
        for (int s = 64; s > 0; s >>= 1) { if (j < s) red[j] += red[j+s]; __syncthreads(); }
        if (j == 0) sConst[0] = red[0] + a_b[0];
    } else {
        // zero deg[] with the 127 otherwise-idle blocks (16256 threads)
        int idx = (k - 1) * 128 + j;
        for (int i = idx; i < N_NODES_C; i += 127 * 128) deg[i] = 0;
    }
}

// ============ K1-mega: MFMA node GEMM + rel table + histogram =============
// blocks [0,782): GEMM  [An|Bn] = ent @ WfT, bf16 out, fused sA/sB (round-7 struct)
// blocks [782,842): 4 rel rows each -> RmB (bf16) + sR
// blocks [842,970): grid-stride histogram of trip[:,0] into deg
__global__ __launch_bounds__(512, 4) void k1_mega(const float* __restrict__ ent,
                                                  const ushort* __restrict__ WfTb,
                                                  const float* __restrict__ a_w,
                                                  const float* __restrict__ relE,
                                                  const float* __restrict__ WR,
                                                  const int* __restrict__ trip,
                                                  ushort* __restrict__ AnB,
                                                  ushort* __restrict__ BnB,
                                                  ushort* __restrict__ RmB,
                                                  float* __restrict__ sA,
                                                  float* __restrict__ sB,
                                                  float* __restrict__ sR,
                                                  int* __restrict__ deg,
                                                  int n_nodes) {
    __shared__ __align__(16) ushort wL[256*128];   // 64 KB (GEMM blocks)
    int tid = threadIdx.x;
    int blk = blockIdx.x;

    if (blk >= NBLK_GEMM + NBLK_REL) {
        // ---- histogram blocks ----
        int hb = blk - NBLK_GEMM - NBLK_REL;
        for (int e = hb*512 + tid; e < N_EDGES_C; e += NBLK_HIST*512) {
            int s = trip[3*e];
            if ((unsigned)s < (unsigned)N_NODES_C) atomicAdd(&deg[s], 1);
        }
        return;
    }
    if (blk >= NBLK_GEMM) {
        // ---- rel blocks: 4 rows each ----
        __shared__ float red[512];
        int sub = tid >> 7, j = tid & 127;
        int r = (blk - NBLK_GEMM)*4 + sub;
        float acc = 0.f;
        if (r < N_RELS_C) {
            for (int k = 0; k < D; ++k) acc += relE[r*D+k] * WR[k*D+j];
            RmB[r*D + j] = f2bf(acc);
        }
        red[tid] = acc * a_w[j];
        __syncthreads();
        for (int s = 64; s > 0; s >>= 1) {
            if (j < s) red[sub*128 + j] += red[sub*128 + j + s];
            __syncthreads();
        }
        if (j == 0 && r < N_RELS_C) sR[r] = red[sub*128];
        return;
    }

    // ---- GEMM blocks (round-7 proven structure) ----
    int m0 = blk * 128;
#pragma unroll
    for (int u = 0; u < 8; ++u) {
        int f = u*512 + tid;          // 0..4095
        int r = f >> 4, k16 = f & 15;
        *(uint4*)&wL[r*128 + ((k16 ^ (r & 15)) << 3)] =
            *(const uint4*)&WfTb[r*128 + (k16 << 3)];
    }
    __syncthreads();

    int wave = tid >> 6, lane = tid & 63;
    int ny = wave >> 2;                 // 0 = A-half, 1 = B-half
    int q = lane >> 4, c = lane & 15;
    int wm = (wave & 3) * 32;

    f32x4 acc[2][8];
#pragma unroll
    for (int mt = 0; mt < 2; ++mt)
#pragma unroll
        for (int nt = 0; nt < 8; ++nt) { f32x4 z = {0.f,0.f,0.f,0.f}; acc[mt][nt] = z; }

#pragma unroll
    for (int chunk = 0; chunk < 4; ++chunk) {
        int k16 = chunk*4 + q;
        short8 a[2];
#pragma unroll
        for (int mt = 0; mt < 2; ++mt) {
            int row = m0 + wm + mt*16 + c;
            float4 e0 = make_float4(0.f,0.f,0.f,0.f), e1 = e0;
            if (row < n_nodes) {
                const float* ep = &ent[(size_t)row*D + (k16 << 3)];
                e0 = *(const float4*)ep;
                e1 = *(const float4*)(ep + 4);
            }
            short8 pk;
            pk[0]=(short)f2bf(e0.x); pk[1]=(short)f2bf(e0.y); pk[2]=(short)f2bf(e0.z); pk[3]=(short)f2bf(e0.w);
            pk[4]=(short)f2bf(e1.x); pk[5]=(short)f2bf(e1.y); pk[6]=(short)f2bf(e1.z); pk[7]=(short)f2bf(e1.w);
            a[mt] = pk;
        }
#pragma unroll
        for (int nt = 0; nt < 8; ++nt) {
            int wrow = ny*128 + nt*16 + c;
            short8 b = *(const short8*)&wL[wrow*128 + ((k16 ^ c) << 3)];
            acc[0][nt] = __builtin_amdgcn_mfma_f32_16x16x32_bf16(a[0], b, acc[0][nt], 0, 0, 0);
            acc[1][nt] = __builtin_amdgcn_mfma_f32_16x16x32_bf16(a[1], b, acc[1][nt], 0, 0, 0);
        }
    }

    float aw[8];
#pragma unroll
    for (int nt = 0; nt < 8; ++nt) aw[nt] = a_w[nt*16 + c];

    ushort* out  = ny ? BnB : AnB;
    float*  sOut = ny ? sB  : sA;

#pragma unroll
    for (int mt = 0; mt < 2; ++mt) {
#pragma unroll
        for (int reg = 0; reg < 4; ++reg) {
            int m = m0 + wm + mt*16 + q*4 + reg;
            float pa = 0.f;
#pragma unroll
            for (int nt = 0; nt < 8; ++nt) pa += acc[mt][nt][reg] * aw[nt];
#pragma unroll
            for (int msk = 1; msk < 16; msk <<= 1) pa += __shfl_xor(pa, msk);
            if (m < n_nodes) {
                if (c == 0) sOut[m] = pa;
#pragma unroll
                for (int nt = 0; nt < 8; ++nt)
                    out[(size_t)m*D + nt*16 + c] = f2bf(acc[mt][nt][reg]);
            }
        }
    }
}

// ============ scan stage 1 (coalesced block-local scan) =============
__global__ void k_scan1(const int* __restrict__ deg, int* __restrict__ off,
                        int* __restrict__ bsum, int n) {
    __shared__ int s[1024];
    int i = blockIdx.x*1024 + threadIdx.x;
    int v = (i < n) ? deg[i] : 0;
    s[threadIdx.x] = v; __syncthreads();
    for (int d = 1; d < 1024; d <<= 1) {
        int t = (threadIdx.x >= d) ? s[threadIdx.x - d] : 0;
        __syncthreads();
        s[threadIdx.x] += t;
        __syncthreads();
    }
    if (i < n) off[i] = s[threadIdx.x] - v;          // exclusive, pre-block-offset
    if (threadIdx.x == 1023) bsum[blockIdx.x] = s[1023];
}

// ============ scan stages 2+3 merged: every block re-scans the 98 bsums ======
__global__ void k_scan23(int* __restrict__ off, int* __restrict__ cursor,
                         const int* __restrict__ bsum, int n, int nb, int total_edges) {
    __shared__ int s[128];
    int t = threadIdx.x;
    if (t < 128) s[t] = (t < nb) ? bsum[t] : 0;
    __syncthreads();
    for (int d = 1; d < 128; d <<= 1) {
        int u = (t < 128 && t >= d) ? s[t - d] : 0;
        __syncthreads();
        if (t < 128) s[t] += u;          // inclusive scan
        __syncthreads();
    }
    int add = (blockIdx.x > 0) ? s[blockIdx.x - 1] : 0;   // exclusive prefix
    int i = blockIdx.x*1024 + t;
    if (i < n) {
        int o = off[i] + add;
        off[i] = o;
        cursor[i] = o;
    }
    if (i == 0) off[n] = total_edges;
}

// ============ K2c: scatter (key, sB[dst]+sR[rel]) record into CSR slot ============
// The exp lives in k_aggregate (sA[src]+const is node-uniform there).
__global__ void k_edge_b(const int* __restrict__ trip, const float* __restrict__ sB,
                         const float* __restrict__ sR, int* __restrict__ cursor,
                         uint2* __restrict__ kb, int n_edges) {
    int e = blockIdx.x*256 + threadIdx.x;
    if (e >= n_edges) return;
    int s = trip[3*e], d = trip[3*e+1], r = trip[3*e+2];
    if ((unsigned)s >= (unsigned)N_NODES_C || (unsigned)d >= (unsigned)N_NODES_C ||
        (unsigned)r >= (unsigned)N_RELS_C) return;   // guard (matches hist)
    float v = sB[d] + sR[r];
    int p = atomicAdd(&cursor[s], 1);
    kb[p] = make_uint2((uint)(d | (r << 20)), __float_as_uint(v));
}

// ============ K3: single-pass node-major aggregation, masked unroll-4 =============
// h[n] = An[n] + biasC + num/den, num = sum_e b_e*(B[dst]+R[rel]), den = sum_e b_e,
// b_e = exp(leaky(sA[n] + v_e + const)). 16 lanes per node (4 chains/wave).
// The edge loop is ALWAYS a 4-wide batch: indices clamped to o1-1, coefficient
// zeroed for invalid slots — every node gets 4-deep memory-level parallelism.
__global__ void k_aggregate(const int* __restrict__ off, const uint2* __restrict__ kb,
                            const ushort* __restrict__ AnB, const ushort* __restrict__ BnB,
                            const ushort* __restrict__ RmB, const float* __restrict__ biasC,
                            const float* __restrict__ sA, const float* __restrict__ sConst,
                            float* __restrict__ h, int n_nodes) {
    int g = threadIdx.x >> 4, lane = threadIdx.x & 15;
    int n = blockIdx.x*16 + g;
    if (n >= n_nodes) return;
    int o0 = off[n], o1 = off[n+1];
    int c = lane*8;
    float* hp = &h[(size_t)n*D + c];
    if (o0 == o1) {
        *(float4*)hp     = make_float4(0.f,0.f,0.f,0.f);
        *(float4*)(hp+4) = make_float4(0.f,0.f,0.f,0.f);
        return;
    }
    float t = sA[n] + sConst[0];
    float num[8];
#pragma unroll
    for (int i = 0; i < 8; ++i) num[i] = 0.f;
    float den = 0.f;

    for (int p = o0; p < o1; p += 4) {
        uint2 kv[4]; uint4 gB[4], gR[4]; float vmask[4];
#pragma unroll
        for (int u = 0; u < 4; ++u) {
            int q = p + u;
            vmask[u] = (q < o1) ? 1.f : 0.f;
            int pc = (q < o1) ? q : (o1 - 1);
            kv[u] = kb[pc];
        }
#pragma unroll
        for (int u = 0; u < 4; ++u) {
            gB[u] = *(const uint4*)&BnB[(size_t)(kv[u].x & 0xFFFFF)*D + c];
            gR[u] = *(const uint4*)&RmB[(size_t)(kv[u].x >> 20)*D + c];
        }
#pragma unroll
        for (int u = 0; u < 4; ++u) {
            float logit = t + __uint_as_float(kv[u].y);
            float l = logit > 0.f ? logit : 0.01f*logit;
            float b = vmask[u] * expf(l);
            den += b;
            const uint* bu = (const uint*)&gB[u];
            const uint* ru = (const uint*)&gR[u];
#pragma unroll
            for (int i = 0; i < 4; ++i) {
                num[2*i]   += b * (bf2f_hi(bu[i] << 16)         + bf2f_hi(ru[i] << 16));
                num[2*i+1] += b * (bf2f_hi(bu[i] & 0xFFFF0000u) + bf2f_hi(ru[i] & 0xFFFF0000u));
            }
        }
    }

    float inv = 1.f / den;
    uint4 araw = *(const uint4*)&AnB[(size_t)n*D + c];
    const uint* au = (const uint*)&araw;
    float4 bc0 = *(const float4*)&biasC[c];
    float4 bc1 = *(const float4*)&biasC[c+4];
    float4 o0v, o1v;
    o0v.x = bf2f_hi(au[0] << 16)         + bc0.x + num[0]*inv;
    o0v.y = bf2f_hi(au[0] & 0xFFFF0000u) + bc0.y + num[1]*inv;
    o0v.z = bf2f_hi(au[1] << 16)         + bc0.z + num[2]*inv;
    o0v.w = bf2f_hi(au[1] & 0xFFFF0000u) + bc0.w + num[3]*inv;
    o1v.x = bf2f_hi(au[2] << 16)         + bc1.x + num[4]*inv;
    o1v.y = bf2f_hi(au[2] & 0xFFFF0000u) + bc1.y + num[5]*inv;
    o1v.z = bf2f_hi(au[3] << 16)         + bc1.z + num[6]*inv;
    o1v.w = bf2f_hi(au[3] & 0xFFFF0000u) + bc1.w + num[7]*inv;
    *(float4*)hp     = o0v;
    *(float4*)(hp+4) = o1v;
}

extern "C" void kernel_launch(void* const* d_in, const int* in_sizes, int n_in,
                              void* d_out, int out_size, void* d_ws, size_t ws_size,
                              hipStream_t stream) {
    const int*   trip   = (const int*)  d_in[0];
    const float* ent    = (const float*)d_in[1];
    const float* relE   = (const float*)d_in[2];
    const float* W_ent  = (const float*)d_in[3];
    const float* b_ent  = (const float*)d_in[4];
    const float* W_rel  = (const float*)d_in[5];
    const float* b_rel  = (const float*)d_in[6];
    const float* W_ent2 = (const float*)d_in[7];
    const float* b_ent2 = (const float*)d_in[8];
    const float* a_w    = (const float*)d_in[9];
    const float* a_b    = (const float*)d_in[10];
    float* h = (float*)d_out;

    // Workspace: ~57 MB total — stays under round 4's proven-safe 57.6 MB.
    char* ws = (char*)d_ws;
    size_t o = 0;
    auto alloc = [&](size_t bytes) { size_t p = o; o += (bytes + 255) & ~(size_t)255; return p; };
    float*  WR     = (float*) (ws + alloc(128*128*4));
    ushort* WfTb   = (ushort*)(ws + alloc(256*128*2));
    float*  biasC  = (float*) (ws + alloc(128*4));
    ushort* RmB    = (ushort*)(ws + alloc((size_t)N_RELS_C*128*2));
    float*  sR     = (float*) (ws + alloc(N_RELS_C*4));
    float*  sConst = (float*) (ws + alloc(4));
    float*  sA     = (float*) (ws + alloc((size_t)N_NODES_C*4));
    float*  sB     = (float*) (ws + alloc((size_t)N_NODES_C*4));
    int*    deg    = (int*)   (ws + alloc((size_t)N_NODES_C*4));
    int*    off    = (int*)   (ws + alloc(((size_t)N_NODES_C+1)*4));
    int*    cursor = (int*)   (ws + alloc((size_t)N_NODES_C*4));
    int*    bsum   = (int*)   (ws + alloc(128*4));
    uint2*  kb     = (uint2*) (ws + alloc((size_t)N_EDGES_C*8));
    ushort* BnB    = (ushort*)(ws + alloc((size_t)N_PAD_C*128*2));
    ushort* AnB    = (ushort*)(ws + alloc((size_t)N_PAD_C*128*2));

    // 6 dispatches total (was 10) — each eliminated launch saves ~8-10 us.
    k_fuse_w<<<dim3(128,4), 128, 0, stream>>>(W_ent, W_rel, W_ent2, b_ent, b_rel, b_ent2,
                                              a_w, a_b, WR, WfTb, biasC, sConst, deg);
    k1_mega<<<NBLK_GEMM + NBLK_REL + NBLK_HIST, 512, 0, stream>>>(
        ent, WfTb, a_w, relE, WR, trip, AnB, BnB, RmB, sA, sB, sR, deg, N_NODES_C);
    int nb = (N_NODES_C + 1023)/1024;   // 98
    k_scan1<<<nb, 1024, 0, stream>>>(deg, off, bsum, N_NODES_C);
    k_scan23<<<nb, 1024, 0, stream>>>(off, cursor, bsum, N_NODES_C, nb, N_EDGES_C);
    k_edge_b<<<(N_EDGES_C+255)/256, 256, 0, stream>>>(trip, sB, sR, cursor, kb, N_EDGES_C);
    k_aggregate<<<(N_NODES_C+15)/16, 256, 0, stream>>>(off, kb, AnB, BnB, RmB, biasC,
                                                       sA, sConst, h, N_NODES_C);
}